// Round 1
// baseline (1004.782 us; speedup 1.0000x reference)
//
#include <hip/hip_runtime.h>

#define NTH 256

// LDS float offsets
#define S_NDS   0        // nodes [96][34]
#define S_AV    3264     // avv / rn / x0 / rfc2 overlay
#define S_W3U   6528     // W3u^T [32][32]
#define S_W5U   7552     // W5u^T [32][32]
#define S_W3W   8576     // W3w^T [64][32]
#define S_W4W   10624    // W4w^T [64][32]
#define S_W5W   12672    // W5w^T [64][32]
#define S_MASK  14720    // mask [16][81]
#define S_TOT   16016    // 64,064 bytes -> 2 blocks/CU

// final-phase overlays (GEMM weights dead after T loop)
#define S_WOT   S_W3U        // Wo^T [64][16]
#define S_WRX   S_W5U        // Wrx^T [32][16]
#define S_WRY   (S_W5U+512)  // Wry^T [32][16]
#define S_OUTB  S_W3W        // out  [96][20] (16B-aligned rows for float4)
#define S_RFCX  S_W4W        // [16][16]
#define S_RFCY  (S_W4W+256)  // [80][16]
#define S_RFC2  S_AV         // [16][80]

__device__ __forceinline__ float sig_(float x) { return 1.0f / (1.0f + __expf(-x)); }
__device__ __forceinline__ float th_(float x)  { return 1.0f - 2.0f / (1.0f + __expf(2.0f * x)); }

union F4 { float4 v; float f[4]; };
union F2 { float2 v; float f[2]; };

__global__ __launch_bounds__(NTH, 2)
void ggnn_fused(const float* __restrict__ input,
                const float* __restrict__ maskp,
                const float* __restrict__ W3w, const float* __restrict__ b3w,
                const float* __restrict__ W3u, const float* __restrict__ b3u,
                const float* __restrict__ W4w, const float* __restrict__ b4w,
                const float* __restrict__ W5w, const float* __restrict__ b5w,
                const float* __restrict__ W5u, const float* __restrict__ b5u,
                const float* __restrict__ Wo,  const float* __restrict__ bo,
                const float* __restrict__ Wrx, const float* __restrict__ brx,
                const float* __restrict__ Wry, const float* __restrict__ bry,
                const float* __restrict__ Wr2, const float* __restrict__ br2,
                float* __restrict__ dout)
{
    __shared__ float S[S_TOT];
    const int tid = threadIdx.x;
    const int b   = blockIdx.x;

    // ---- stage transposed weights into LDS ----
    for (int t = tid; t < 1024; t += NTH) {
        const int h = t >> 5, k = t & 31;
        S[S_W3U + k*32 + h] = W3u[t];
        S[S_W5U + k*32 + h] = W5u[t];
    }
    for (int t = tid; t < 2048; t += NTH) {
        const int h = t >> 6, k = t & 63;
        S[S_W3W + k*32 + h] = W3w[t];
        S[S_W4W + k*32 + h] = W4w[t];
        S[S_W5W + k*32 + h] = W5w[t];
    }
    for (int t = tid; t < 1280; t += NTH) {
        const int c = t / 80, o = t - c*80;
        S[S_MASK + c*81 + o] = maskp[t];
    }
    const float* xin = input + (size_t)b * 3072;
    for (int t = tid; t < 3072; t += NTH) {
        const int i = t >> 5, h = t & 31;
        S[S_NDS + i*34 + h] = xin[t];
    }

    const int a  = tid & 31;   // node lane (pass1/pass2) / h lane (phase A)
    const int bq = tid >> 5;   // h-quad group (pass1) / node-stripe group (phase A)
    const int h0 = bq << 2;
    const int i0 = a, i1 = a + 32, i2 = a + 64;
    const bool isC = (a < 16);

    float bu_[4], bz_[4], br_[4], bh_[4];
    #pragma unroll
    for (int q = 0; q < 4; ++q) {
        bu_[q] = b3u[h0+q];
        bz_[q] = b3w[h0+q];
        br_[q] = b4w[h0+q];
        bh_[q] = b5w[h0+q] + b5u[h0+q];  // hv bias = b5w + b5u
    }
    __syncthreads();

    for (int it = 0; it < 5; ++it) {
        // ---- Phase A: avv = (block-structured) A @ nodes, lane = h, group = node stripe ----
        {
            // C-targets (i = bq, bq+8 < 16): a_in = sum_o mask[i][o] * nodes[16+o]
            float a0 = 0.f, a1 = 0.f;
            #pragma unroll 8
            for (int o = 0; o < 80; ++o) {
                const float v = S[S_NDS + (16+o)*34 + a];
                a0 = fmaf(S[S_MASK + bq*81 + o],     v, a0);
                a1 = fmaf(S[S_MASK + (bq+8)*81 + o], v, a1);
            }
            S[S_AV + bq*34 + a]     = a0;
            S[S_AV + (bq+8)*34 + a] = a1;

            // O-targets (i = 16+o): a_out = sum_c mask[c][o] * nodes[c]; hoist nodes[c][h]
            float vc[16];
            #pragma unroll
            for (int c = 0; c < 16; ++c) vc[c] = S[S_NDS + c*34 + a];
            #pragma unroll
            for (int tp = 0; tp < 10; ++tp) {
                const int o0 = bq + 8*tp;
                float acc = 0.f;
                #pragma unroll
                for (int c = 0; c < 16; ++c)
                    acc = fmaf(S[S_MASK + c*81 + o0], vc[c], acc);
                S[S_AV + (16+o0)*34 + a] = acc;
            }
        }
        __syncthreads();

        // ---- Pass 1: u3, z, r, h-partial; thread = 3 nodes x 4 h ----
        float u0[4],u1[4],u2[4],z0[4],z1[4],z2[4],r0[4],r1[4],r2[4],g0[4],g1[4],g2[4];
        #pragma unroll
        for (int q = 0; q < 4; ++q) {
            u0[q]=bu_[q]; u1[q]=bu_[q]; u2[q]=bu_[q];
            z0[q]=bz_[q]; z1[q]=bz_[q]; z2[q]=bz_[q];
            r0[q]=br_[q]; r1[q]=br_[q]; r2[q]=br_[q];
            g0[q]=bh_[q]; g1[q]=bh_[q]; g2[q]=bh_[q];
        }
        #pragma unroll 2
        for (int k = 0; k < 32; ++k) {
            const float vn0 = S[S_NDS + i0*34 + k];
            const float vn1 = S[S_NDS + i1*34 + k];
            const float vn2 = S[S_NDS + i2*34 + k];
            const float va0 = S[S_AV + i0*34 + k];
            const float va1 = S[S_AV + i1*34 + k];
            const float va2 = S[S_AV + i2*34 + k];
            F4 wu, wzC, wzO, wrC, wrO, whC, whO;
            wu.v  = *(const float4*)&S[S_W3U + k*32 + h0];
            wzC.v = *(const float4*)&S[S_W3W + k*32 + h0];
            wzO.v = *(const float4*)&S[S_W3W + (k+32)*32 + h0];
            wrC.v = *(const float4*)&S[S_W4W + k*32 + h0];
            wrO.v = *(const float4*)&S[S_W4W + (k+32)*32 + h0];
            whC.v = *(const float4*)&S[S_W5W + k*32 + h0];
            whO.v = *(const float4*)&S[S_W5W + (k+32)*32 + h0];
            #pragma unroll
            for (int q = 0; q < 4; ++q) {
                const float wuq = wu.f[q];
                u0[q] = fmaf(wuq, vn0, u0[q]);
                u1[q] = fmaf(wuq, vn1, u1[q]);
                u2[q] = fmaf(wuq, vn2, u2[q]);
                const float wz0 = isC ? wzC.f[q] : wzO.f[q];
                const float wr0 = isC ? wrC.f[q] : wrO.f[q];
                const float wh0 = isC ? whC.f[q] : whO.f[q];
                z0[q] = fmaf(wz0,      va0, z0[q]);
                z1[q] = fmaf(wzO.f[q], va1, z1[q]);
                z2[q] = fmaf(wzO.f[q], va2, z2[q]);
                r0[q] = fmaf(wr0,      va0, r0[q]);
                r1[q] = fmaf(wrO.f[q], va1, r1[q]);
                r2[q] = fmaf(wrO.f[q], va2, r2[q]);
                g0[q] = fmaf(wh0,      va0, g0[q]);
                g1[q] = fmaf(whO.f[q], va1, g1[q]);
                g2[q] = fmaf(whO.f[q], va2, g2[q]);
            }
        }
        float nd0[4], nd1[4], nd2[4];
        #pragma unroll
        for (int q = 0; q < 4; ++q) {
            nd0[q] = S[S_NDS + i0*34 + h0 + q];
            nd1[q] = S[S_NDS + i1*34 + h0 + q];
            nd2[q] = S[S_NDS + i2*34 + h0 + q];
        }
        __syncthreads();           // all pass1 reads of avv done
        #pragma unroll
        for (int q = 0; q < 4; ++q) {   // rn = sigmoid(r+u) * nodes  (overwrites avv)
            S[S_AV + i0*34 + h0 + q] = sig_(r0[q] + u0[q]) * nd0[q];
            S[S_AV + i1*34 + h0 + q] = sig_(r1[q] + u1[q]) * nd1[q];
            S[S_AV + i2*34 + h0 + q] = sig_(r2[q] + u2[q]) * nd2[q];
        }
        __syncthreads();
        // ---- Pass 2: g += rn @ W5u^T ----
        #pragma unroll 4
        for (int k = 0; k < 32; ++k) {
            const float rk0 = S[S_AV + i0*34 + k];
            const float rk1 = S[S_AV + i1*34 + k];
            const float rk2 = S[S_AV + i2*34 + k];
            F4 w5; w5.v = *(const float4*)&S[S_W5U + k*32 + h0];
            #pragma unroll
            for (int q = 0; q < 4; ++q) {
                g0[q] = fmaf(w5.f[q], rk0, g0[q]);
                g1[q] = fmaf(w5.f[q], rk1, g1[q]);
                g2[q] = fmaf(w5.f[q], rk2, g2[q]);
            }
        }
        // ---- update: nodes = nodes + z*(tanh(g) - nodes) ----
        #pragma unroll
        for (int q = 0; q < 4; ++q) {
            const float zz0 = sig_(z0[q] + u0[q]);
            const float zz1 = sig_(z1[q] + u1[q]);
            const float zz2 = sig_(z2[q] + u2[q]);
            S[S_NDS + i0*34 + h0 + q] = fmaf(zz0, th_(g0[q]) - nd0[q], nd0[q]);
            S[S_NDS + i1*34 + h0 + q] = fmaf(zz1, th_(g1[q]) - nd1[q], nd1[q]);
            S[S_NDS + i2*34 + h0 + q] = fmaf(zz2, th_(g2[q]) - nd2[q], nd2[q]);
        }
        __syncthreads();
    }

    // ---- final head ----
    for (int t = tid; t < 3072; t += NTH) {            // x0 -> AV area
        const int i = t >> 5, h = t & 31;
        S[S_AV + i*34 + h] = xin[t];
    }
    for (int t = tid; t < 1024; t += NTH) {            // Wo^T overlay
        const int j = t >> 6, k = t & 63;
        S[S_WOT + k*16 + j] = Wo[t];
    }
    for (int t = tid; t < 512; t += NTH) {             // Wrx^T / Wry^T overlay
        const int j = t >> 5, k = t & 31;
        S[S_WRX + k*16 + j] = Wrx[t];
        S[S_WRY + k*16 + j] = Wry[t];
    }
    __syncthreads();

    {   // out = tanh([nodes, x0] @ Wo^T + bo), thread = 3 nodes x 2 j
        const int j2 = bq * 2;
        float oa0[2], oa1[2], oa2[2];
        #pragma unroll
        for (int q = 0; q < 2; ++q) { oa0[q] = bo[j2+q]; oa1[q] = bo[j2+q]; oa2[q] = bo[j2+q]; }
        #pragma unroll 2
        for (int k = 0; k < 32; ++k) {
            const float vn0 = S[S_NDS + i0*34 + k];
            const float vn1 = S[S_NDS + i1*34 + k];
            const float vn2 = S[S_NDS + i2*34 + k];
            const float vx0 = S[S_AV + i0*34 + k];
            const float vx1 = S[S_AV + i1*34 + k];
            const float vx2 = S[S_AV + i2*34 + k];
            F2 wn, wx;
            wn.v = *(const float2*)&S[S_WOT + k*16 + j2];
            wx.v = *(const float2*)&S[S_WOT + (32+k)*16 + j2];
            #pragma unroll
            for (int q = 0; q < 2; ++q) {
                oa0[q] = fmaf(wn.f[q], vn0, oa0[q]); oa0[q] = fmaf(wx.f[q], vx0, oa0[q]);
                oa1[q] = fmaf(wn.f[q], vn1, oa1[q]); oa1[q] = fmaf(wx.f[q], vx1, oa1[q]);
                oa2[q] = fmaf(wn.f[q], vn2, oa2[q]); oa2[q] = fmaf(wx.f[q], vx2, oa2[q]);
            }
        }
        #pragma unroll
        for (int q = 0; q < 2; ++q) {
            S[S_OUTB + i0*20 + j2 + q] = th_(oa0[q]);
            S[S_OUTB + i1*20 + j2 + q] = th_(oa1[q]);
            S[S_OUTB + i2*20 + j2 + q] = th_(oa2[q]);
        }
    }
    {   // rfcx / rfcy, thread = (j, group)
        const int jj = tid & 15, grp = tid >> 4;
        float ax = brx[jj];
        #pragma unroll 4
        for (int k = 0; k < 32; ++k)
            ax = fmaf(S[S_WRX + k*16 + jj], S[S_NDS + grp*34 + k], ax);
        S[S_RFCX + grp*16 + jj] = th_(ax);

        float ay[5];
        #pragma unroll
        for (int t2 = 0; t2 < 5; ++t2) ay[t2] = bry[jj];
        #pragma unroll 2
        for (int k = 0; k < 32; ++k) {
            const float w = S[S_WRY + k*16 + jj];
            #pragma unroll
            for (int t2 = 0; t2 < 5; ++t2)
                ay[t2] = fmaf(w, S[S_NDS + (16 + grp + 16*t2)*34 + k], ay[t2]);
        }
        #pragma unroll
        for (int t2 = 0; t2 < 5; ++t2)
            S[S_RFCY + (grp + 16*t2)*16 + jj] = th_(ay[t2]);
    }
    __syncthreads();

    {   // rfc2 = sigmoid(sum_j Wr2[j]*rfcx[c][j]*rfcy[o][j] + br2) * mask
        float wr2r[16];
        #pragma unroll
        for (int j = 0; j < 16; ++j) wr2r[j] = Wr2[j];
        const float br2v = br2[0];
        #pragma unroll
        for (int t2 = 0; t2 < 5; ++t2) {
            const int idx = tid + NTH*t2;          // 0..1279
            const int c = idx / 80;
            const int o = idx - c*80;
            float s = br2v;
            #pragma unroll
            for (int j = 0; j < 16; ++j)
                s = fmaf(wr2r[j], S[S_RFCX + c*16 + j] * S[S_RFCY + o*16 + j], s);
            S[S_RFC2 + idx] = sig_(s) * S[S_MASK + c*81 + o];
        }
    }
    __syncthreads();

    {   // final: (16, 81, 16) per graph; coalesced float4 stores
        float* doutb = dout + (size_t)b * 20736;
        #pragma unroll
        for (int t2 = 0; t2 < 21; ++t2) {
            const int f4 = tid + NTH*t2;           // quad index, 0..5183
            if (f4 < 5184) {
                const int f   = f4 << 2;
                const int c   = f / 1296;          // 81*16
                const int rem = f - c*1296;
                const int co  = rem >> 4;
                const int k   = rem & 15;          // multiple of 4
                float4 v;
                if (co == 0) {
                    v = *(const float4*)&S[S_OUTB + c*20 + k];
                } else {
                    const float sc = S[S_RFC2 + c*80 + (co - 1)];
                    const float4 ov = *(const float4*)&S[S_OUTB + (16 + co - 1)*20 + k];
                    v.x = ov.x*sc; v.y = ov.y*sc; v.z = ov.z*sc; v.w = ov.w*sc;
                }
                *(float4*)&doutb[f] = v;
            }
        }
    }
}

extern "C" void kernel_launch(void* const* d_in, const int* in_sizes, int n_in,
                              void* d_out, int out_size, void* d_ws, size_t ws_size,
                              hipStream_t stream) {
    const float* input = (const float*)d_in[0];
    // d_in[1]=in_mat, d_in[2]=out_mat are implied by mask (=mat) and skipped
    const float* maskp = (const float*)d_in[3];
    const float* W3w = (const float*)d_in[4];  const float* b3w = (const float*)d_in[5];
    const float* W3u = (const float*)d_in[6];  const float* b3u = (const float*)d_in[7];
    const float* W4w = (const float*)d_in[8];  const float* b4w = (const float*)d_in[9];
    const float* W5w = (const float*)d_in[10]; const float* b5w = (const float*)d_in[11];
    const float* W5u = (const float*)d_in[12]; const float* b5u = (const float*)d_in[13];
    const float* Wo  = (const float*)d_in[14]; const float* bo  = (const float*)d_in[15];
    const float* Wrx = (const float*)d_in[16]; const float* brx = (const float*)d_in[17];
    const float* Wry = (const float*)d_in[18]; const float* bry = (const float*)d_in[19];
    const float* Wr2 = (const float*)d_in[20]; const float* br2 = (const float*)d_in[21];

    ggnn_fused<<<dim3(4096), dim3(NTH), 0, stream>>>(
        input, maskp, W3w, b3w, W3u, b3u, W4w, b4w, W5w, b5w, W5u, b5u,
        Wo, bo, Wrx, brx, Wry, bry, Wr2, br2, (float*)d_out);
}